// Round 2
// baseline (431.558 us; speedup 1.0000x reference)
//
#include <hip/hip_runtime.h>
#include <cstdint>
#include <cstddef>

typedef _Float16 f16;
typedef f16 f16x8 __attribute__((ext_vector_type(8)));
typedef float f32x4 __attribute__((ext_vector_type(4)));

#define L2E 1.44269504088896340736f

static __device__ __forceinline__ uint32_t pack2(float a, float b){
  union { f16 h[2]; uint32_t u; } t;
  t.h[0] = (f16)a; t.h[1] = (f16)b;
  return t.u;
}

static __device__ __forceinline__ f16x8 frag2(uint32_t u0, uint32_t u1){
  union { uint32_t u[4]; f16x8 v; } t;
  t.u[0] = u0; t.u[1] = u1; t.u[2] = 0u; t.u[3] = 0u;
  return t.v;
}

// ws layout (uint32 units):
//   [0, 8192)      LSTM W_hh chunks 0,1 : [tile16][chunk2][lane64][reg4]
//   [8192, 8704)   LSTM ext chunk       : [tile16][lane16][2]  (Wih*s pair, bias*s)
//   [8704, 11776)  fc1_w1 (+b1)         : [tile4][chunk3][lane64][reg4]
//   [11776, 14848) fc1_w2 (+b2)
//   [14848, 17920) fo_w1  (+b1)
//   [17920, 18688) fo_w2  (+b2)         : [tile1][chunk3][lane64][reg4]
__global__ void prep_kernel(const float* __restrict__ Wih, const float* __restrict__ Whh,
                            const float* __restrict__ bih, const float* __restrict__ bhh,
                            const float* __restrict__ w1, const float* __restrict__ B1,
                            const float* __restrict__ w2, const float* __restrict__ B2,
                            const float* __restrict__ w3, const float* __restrict__ B3,
                            const float* __restrict__ w4, const float* __restrict__ B4,
                            uint32_t* __restrict__ ws){
  int idx = blockIdx.x*256 + threadIdx.x;
  if (idx >= 18688) return;
  if (idx < 8192){
    int reg = idx & 3, ln = (idx>>2)&63, tc = idx>>8;
    int chunk = tc & 1, tile = tc >> 1;
    int j = tile*16 + (ln & 15);
    int kb = chunk*32 + (ln>>4)*8 + reg*2;
    float s = (j >= 128 && j < 192) ? 2.0f*L2E : L2E;
    ws[idx] = pack2(Whh[j*64+kb]*s, Whh[j*64+kb+1]*s);
  } else if (idx < 8704){
    int l = idx - 8192;
    int e = l & 1, ln = (l>>1)&15, tile = l>>5;
    int j = tile*16 + ln;
    float s = (j >= 128 && j < 192) ? 2.0f*L2E : L2E;
    float v0, v1;
    if (e == 0){ v0 = Wih[j*2]*s; v1 = Wih[j*2+1]*s; }
    else       { v0 = (bih[j]+bhh[j])*s; v1 = 0.f; }
    ws[idx] = pack2(v0, v1);
  } else {
    int l = idx - 8704;
    const float *W, *Bv; int nj;
    if (l < 3072)      { W=w1; Bv=B1; nj=64; }
    else if (l < 6144) { W=w2; Bv=B2; nj=64; l -= 3072; }
    else if (l < 9216) { W=w3; Bv=B3; nj=64; l -= 6144; }
    else               { W=w4; Bv=B4; nj=2;  l -= 9216; }
    int reg = l & 3, ln = (l>>2)&63, tc = l>>8;
    int chunk = tc % 3, tile = tc / 3;
    int j = tile*16 + (ln & 15);
    int kb = chunk*32 + (ln>>4)*8 + reg*2;
    float v0 = 0.f, v1 = 0.f;
    if (j < nj){
      int k0 = kb, k1 = kb+1;
      v0 = (k0 < 64) ? W[j*64+k0] : ((k0==64) ? Bv[j] : 0.f);
      v1 = (k1 < 64) ? W[j*64+k1] : ((k1==64) ? Bv[j] : 0.f);
    }
    ws[idx] = pack2(v0, v1);
  }
}

// 256 blocks x 512 threads; wave = 16 batch rows; 8 waves/block (wave-private state).
__global__ void __launch_bounds__(512, 2)
lstm_main(const float* __restrict__ x, const uint32_t* __restrict__ ws,
          float* __restrict__ out, const int* __restrict__ olp){
  __shared__ __attribute__((aligned(16))) uint32_t Lw[8192];     // 32 KB LSTM W chunks 0,1
  __shared__ uint32_t LextS[512];                                // 2 KB  LSTM ext chunk
  __shared__ __attribute__((aligned(16))) f16 hball[8192];       // 16 KB per-wave h buffers (swizzled)
  __shared__ uint32_t xb[8][16][8];                              // 4 KB  packed fp16 (x0,x1) per t; slot7 = last
  __shared__ float lastb[8][16][2];                              // 1 KB  fp32 carry "last"

  const int tid  = threadIdx.x;
  const int lane = tid & 63;
  const int wave = tid >> 6;
  const int c0   = lane & 15;     // A row / C col / B col within tile
  const int hi   = lane >> 4;     // k-group (A/B), row-group (C)
  const int batch0 = blockIdx.x*128 + wave*16;
  const int OL = olp[0];
  const int ostride = OL*2;

  // stage weights + init buffers
  for (int i = tid; i < 8192; i += 512) Lw[i] = ws[i];
  if (tid < 512) LextS[tid] = ws[8192 + tid];
  for (int i = tid; i < 4096; i += 512) *(uint32_t*)&hball[2*i] = 0u;  // h0 = 0
  if (tid < 128){
    int w = tid >> 4, r = tid & 15;
    const float* xp = x + (size_t)(blockIdx.x*128 + w*16 + r)*16;
    #pragma unroll 1
    for (int t = 0; t < 8; ++t){
      float a = xp[2*t], b = xp[2*t+1];
      xb[w][r][t] = pack2(a, b);
      if (t == 7){ lastb[w][r][0] = a; lastb[w][r][1] = b; }
    }
  }
  __syncthreads();

  const f32x4 zero4 = {0.f, 0.f, 0.f, 0.f};
  f32x4 cst[4];                      // c state: cst[Tg][rr] <-> (row hi*4+rr, j = Tg*16+c0)
  cst[0]=zero4; cst[1]=zero4; cst[2]=zero4; cst[3]=zero4;

  const int hbase = wave*1024;       // halves
  auto readA = [&](int chunk)->f16x8{
    int bo = (c0<<7) | (chunk<<6) | (hi<<4);
    bo ^= ((c0 & 7) << 4);           // XOR swizzle: bank-conflict-free
    return *(const f16x8*)&hball[hbase + (bo>>1)];
  };
  auto writeA = [&](int chunk, f16x8 v){
    int bo = (c0<<7) | (chunk<<6) | (hi<<4);
    bo ^= ((c0 & 7) << 4);
    *(f16x8*)&hball[hbase + (bo>>1)] = v;
  };
  auto hwrite = [&](int brow, int j, float v){
    int bo = (((brow<<6) | j) << 1) ^ ((brow & 7) << 4);
    hball[hbase + (bo>>1)] = (f16)v;
  };

  const f16x8 aone = frag2(hi==0 ? 0x00003C00u : 0u, 0u);  // A ext frag: 1.0 at k=0
  const uint32_t* wsF1 = ws + 8704;
  const uint32_t* wsF2 = ws + 11776;
  const uint32_t* wsG1 = ws + 14848;
  const uint32_t* wsG2 = ws + 17920;

  auto fcTile = [&](const uint32_t* base, int T, f16x8 i0, f16x8 i1)->f32x4{
    const f16x8 b0 = *(const f16x8*)(base + ((size_t)(T*3+0)*64 + lane)*4);
    const f16x8 b1 = *(const f16x8*)(base + ((size_t)(T*3+1)*64 + lane)*4);
    const f16x8 b2 = *(const f16x8*)(base + ((size_t)(T*3+2)*64 + lane)*4);
    f32x4 a = __builtin_amdgcn_mfma_f32_16x16x32_f16(i0, b0, zero4, 0,0,0);
    a = __builtin_amdgcn_mfma_f32_16x16x32_f16(i1, b1, a, 0,0,0);
    a = __builtin_amdgcn_mfma_f32_16x16x32_f16(aone, b2, a, 0,0,0);
    return a;
  };

  #pragma unroll 1
  for (int it = 0; it < OL; ++it){
    // ---- 8 LSTM steps ----
    #pragma unroll 1
    for (int t = 0; t < 8; ++t){
      f16x8 a0 = readA(0);
      f16x8 a1 = readA(1);
      uint32_t xu = 0u, ou = 0u;
      if (hi == 0){ xu = xb[wave][c0][t]; ou = 0x00003C00u; }
      f16x8 ax = frag2(xu, ou);      // A ext: [x0, x1, 1, 0...] (t==7 slot holds last)
      f32x4 acc[16];
      #pragma unroll
      for (int T = 0; T < 16; ++T){
        const f16x8 b0 = *(const f16x8*)&Lw[(size_t)((T*2+0)*64 + lane)*4];
        const f16x8 b1 = *(const f16x8*)&Lw[(size_t)((T*2+1)*64 + lane)*4];
        uint32_t e0 = 0u, e1 = 0u;
        if (hi == 0){ e0 = LextS[(T*16 + c0)*2]; e1 = LextS[(T*16 + c0)*2 + 1]; }
        f16x8 bx = frag2(e0, e1);    // B ext: rows k=64,65 -> Wih*s ; k=66 -> bias*s
        f32x4 a = __builtin_amdgcn_mfma_f32_16x16x32_f16(a0, b0, zero4, 0,0,0);
        a = __builtin_amdgcn_mfma_f32_16x16x32_f16(a1, b1, a, 0,0,0);
        a = __builtin_amdgcn_mfma_f32_16x16x32_f16(ax, bx, a, 0,0,0);
        acc[T] = a;                  // z' (pre-scaled by log2e; 2*log2e for g)
      }
      // gates: i=tiles0-3, f=4-7, g=8-11, o=12-15
      #pragma unroll
      for (int Tg = 0; Tg < 4; ++Tg){
        #pragma unroll
        for (int rr = 0; rr < 4; ++rr){
          float zi = acc[Tg][rr];
          float zf = acc[Tg+4][rr];
          float zg = acc[Tg+8][rr];
          float zo = acc[Tg+12][rr];
          float si = __builtin_amdgcn_rcpf(1.0f + __builtin_amdgcn_exp2f(-zi));
          float sf = __builtin_amdgcn_rcpf(1.0f + __builtin_amdgcn_exp2f(-zf));
          float rg = __builtin_amdgcn_rcpf(1.0f + __builtin_amdgcn_exp2f(-zg));
          float so = __builtin_amdgcn_rcpf(1.0f + __builtin_amdgcn_exp2f(-zo));
          float tg = 2.0f*rg - 1.0f;                 // tanh(g)
          float cv = sf*cst[Tg][rr] + si*tg;
          cst[Tg][rr] = cv;
          float tc = 2.0f*__builtin_amdgcn_rcpf(1.0f + __builtin_amdgcn_exp2f(-2.0f*L2E*cv)) - 1.0f;
          float hv = so*tc;
          hwrite(hi*4 + rr, Tg*16 + c0, hv);
        }
      }
      __syncthreads();
    }

    // ---- FC head ----
    f16x8 hA0 = readA(0);
    f16x8 hA1 = readA(1);            // keep h for restore (carry to next iter)
    {
      f32x4 yy[4];
      #pragma unroll
      for (int T = 0; T < 4; ++T) yy[T] = fcTile(wsF1, T, hA0, hA1);
      #pragma unroll
      for (int T = 0; T < 4; ++T){
        #pragma unroll
        for (int rr = 0; rr < 4; ++rr){
          float v = yy[T][rr];
          v = fmaxf(v, 0.1f*v);      // leaky
          hwrite(hi*4+rr, T*16+c0, v);
        }
      }
    }
    __syncthreads();
    {
      f16x8 i0 = readA(0), i1 = readA(1);
      f32x4 yy[4];
      #pragma unroll
      for (int T = 0; T < 4; ++T) yy[T] = fcTile(wsF2, T, i0, i1);
      #pragma unroll
      for (int T = 0; T < 4; ++T){
        #pragma unroll
        for (int rr = 0; rr < 4; ++rr){
          hwrite(hi*4+rr, T*16+c0, yy[T][rr]);   // no activation
        }
      }
    }
    __syncthreads();
    {
      f16x8 i0 = readA(0), i1 = readA(1);
      f32x4 yy[4];
      #pragma unroll
      for (int T = 0; T < 4; ++T) yy[T] = fcTile(wsG1, T, i0, i1);
      #pragma unroll
      for (int T = 0; T < 4; ++T){
        #pragma unroll
        for (int rr = 0; rr < 4; ++rr){
          float v = yy[T][rr];
          v = fmaxf(v, 0.1f*v);      // leaky
          hwrite(hi*4+rr, T*16+c0, v);
        }
      }
    }
    __syncthreads();
    {
      f16x8 i0 = readA(0), i1 = readA(1);
      f32x4 o = fcTile(wsG2, 0, i0, i1);   // only cols 0,1 valid
      if (c0 < 2){
        #pragma unroll
        for (int rr = 0; rr < 4; ++rr){
          int brow = hi*4 + rr;
          float v = o[rr];
          out[(size_t)(batch0 + brow)*ostride + it*2 + c0] = v;
          lastb[wave][brow][c0] += v;
        }
      }
    }
    __syncthreads();
    writeA(0, hA0);                  // restore h into the (clobbered) buffer
    writeA(1, hA1);
    if (hi == 0){
      xb[wave][c0][7] = pack2(lastb[wave][c0][0], lastb[wave][c0][1]);
    }
    __syncthreads();
  }
}

extern "C" void kernel_launch(void* const* d_in, const int* in_sizes, int n_in,
                              void* d_out, int out_size, void* d_ws, size_t ws_size,
                              hipStream_t stream){
  const float* x    = (const float*)d_in[0];
  const float* Wih  = (const float*)d_in[2];
  const float* Whh  = (const float*)d_in[3];
  const float* bih  = (const float*)d_in[4];
  const float* bhh  = (const float*)d_in[5];
  const float* f1w1 = (const float*)d_in[6];
  const float* f1b1 = (const float*)d_in[7];
  const float* f1w2 = (const float*)d_in[8];
  const float* f1b2 = (const float*)d_in[9];
  const float* fow1 = (const float*)d_in[10];
  const float* fob1 = (const float*)d_in[11];
  const float* fow2 = (const float*)d_in[12];
  const float* fob2 = (const float*)d_in[13];
  const int*   olp  = (const int*)d_in[14];
  uint32_t* ws = (uint32_t*)d_ws;

  hipLaunchKernelGGL(prep_kernel, dim3(73), dim3(256), 0, stream,
                     Wih, Whh, bih, bhh, f1w1, f1b1, f1w2, f1b2,
                     fow1, fob1, fow2, fob2, ws);
  hipLaunchKernelGGL(lstm_main, dim3(256), dim3(512), 0, stream,
                     x, ws, (float*)d_out, olp);
}